// Round 4
// baseline (112.687 us; speedup 1.0000x reference)
//
#include <hip/hip_runtime.h>

// Problem constants (match reference)
#define C_   64
#define H_   256
#define W_   256
#define L0_  1024   // j axis (g0 -> y taps)
#define L1_  1024   // i axis (g1 -> x taps)
#define JT   64     // j-tile per block == wavefront size
#define HYR  258    // hy rows: xk = x_tap + 1, x_tap in [-1, 256]

// Bicubic tap weights, matches PyTorch grid_sample
// (bicubic, padding_mode='border', align_corners=True), A = -0.75.
__device__ __forceinline__ void cubic_weights(float t, float w[4]) {
    const float A = -0.75f;
    float t2 = t * t, t3 = t2 * t;
    w[0] = A * (t3 - 2.0f * t2 + t);
    w[1] = (A + 2.0f) * t3 - (A + 3.0f) * t2 + 1.0f;
    float s = 1.0f - t, s2 = s * s;
    w[2] = (A + 2.0f) * s2 * s - (A + 3.0f) * s2 + 1.0f;
    float u = 2.0f - t, u2 = u * u;
    w[3] = A * u2 * u - 5.0f * A * u2 + 8.0f * A * u - 4.0f * A;
}

// Y-FIRST separable bicubic, JT=64 so phase-2 i is wave-uniform.
//   hy[xk][j] at slot xk*64 + (j ^ (xk&31));  xk = x_tap + 1 with replicated
//   border rows xk=0,256,257 -> phase 2 needs no per-tap clamps.
//   Phase 1: lane = x (4 chunks of 64); contiguous 256B row loads; swizzled
//            scalar writes are conflict-free (xk&31 distinct across lanes).
//   Phase 2: one i per wave-instr; x-weights/indices recomputed inline on the
//            VALU (wave-uniform -> no LDS table reads, the round-1 41->23 cyc
//            win); 4 tap reads are full-wave contiguous 256B b32 (2-way, free);
//            stores are 256B contiguous.
__global__ __launch_bounds__(256, 2) void bicubic_y64(const float* __restrict__ v,
                                                      const float* __restrict__ g0,
                                                      const float* __restrict__ g1,
                                                      float* __restrict__ out) {
    __shared__ float hy[HYR * JT];   // 66 KB -> 2 blocks/CU

    const int t = threadIdx.x;

    // XCD-bijective decode: bid%8 = XCD on dispatch; give each XCD 8 whole
    // channels so a channel's 16 j-tiles share one XCD L2 (16x re-read hits).
    const int bid = blockIdx.x;                 // 0..1023
    const int c   = (bid & 7) * 8 + ((bid >> 3) >> 4);
    const int j0  = ((bid >> 3) & 15) * JT;

    const int lane = t & 63;
    const int wv   = t >> 6;

    // ---- phase 1: y-interp 64 image columns per lane-chunk, 16 j per wave ----
    {
        const float* vc = v + (size_t)c * (H_ * W_);
        for (int jj = 0; jj < 16; ++jj) {
            const int j  = wv * 16 + jj;
            float gj = g0[j0 + j];
            float x  = (gj + 1.0f) * 0.5f * (float)(H_ - 1);
            float x0 = floorf(x);
            int   iy = (int)x0;
            float wy[4]; cubic_weights(x - x0, wy);
            const int y0 = min(max(iy - 1, 0), H_ - 1);
            const int y1 = min(max(iy,     0), H_ - 1);
            const int y2 = min(max(iy + 1, 0), H_ - 1);
            const int y3 = min(max(iy + 2, 0), H_ - 1);
            const float* r0 = vc + y0 * W_;
            const float* r1 = vc + y1 * W_;
            const float* r2 = vc + y2 * W_;
            const float* r3 = vc + y3 * W_;
#pragma unroll
            for (int k = 0; k < 4; ++k) {
                const int x_ = lane + 64 * k;           // 256B contiguous loads
                float val = wy[0] * r0[x_] + wy[1] * r1[x_]
                          + wy[2] * r2[x_] + wy[3] * r3[x_];
                const int xk = x_ + 1;
                hy[xk * JT + (j ^ (xk & 31))] = val;    // conflict-free scalar
                if (x_ == 0)   hy[j] = val;             // pad row xk=0  (x=-1)
                if (x_ == 255) {                        // pad rows 256,257
                    hy[256 * JT + j]       = val;       // 256&31 = 0
                    hy[257 * JT + (j ^ 1)] = val;       // 257&31 = 1
                }
            }
        }
    }
    __syncthreads();

    // ---- phase 2: x-interp; i wave-uniform; weights recomputed inline ----
    {
        float* oc = out + (size_t)c * ((size_t)L1_ * L0_) + j0 + lane;
#pragma unroll 4
        for (int it2 = 0; it2 < 256; ++it2) {
            const int i = wv * 256 + it2;               // wave owns 256 i's
            float gi = g1[i];                           // uniform -> broadcast
            float x  = (gi + 1.0f) * 0.5f * (float)(W_ - 1);
            float x0 = floorf(x);
            int   ix = (int)x0;
            ix = min(max(ix, 0), W_ - 2);               // memory-safety only
            float wx[4]; cubic_weights(x - x0, wx);
            const int b = ix * JT;                      // xk = ix .. ix+3
            float o = wx[0] * hy[b            + (lane ^ ( ix      & 31))]
                    + wx[1] * hy[b +     JT   + (lane ^ ((ix + 1) & 31))]
                    + wx[2] * hy[b + 2 * JT   + (lane ^ ((ix + 2) & 31))]
                    + wx[3] * hy[b + 3 * JT   + (lane ^ ((ix + 3) & 31))];
            oc[(size_t)i * L0_] = o;                    // 256B contiguous store
        }
    }
}

extern "C" void kernel_launch(void* const* d_in, const int* in_sizes, int n_in,
                              void* d_out, int out_size, void* d_ws, size_t ws_size,
                              hipStream_t stream) {
    const float* values = (const float*)d_in[0];  // (1, C, H, W) fp32
    const float* g0     = (const float*)d_in[1];  // (L0,) fp32 -> y axis
    const float* g1     = (const float*)d_in[2];  // (L1,) fp32 -> x axis
    float* out          = (float*)d_out;          // (1, C, L1, L0) fp32

    dim3 grid(C_ * (L0_ / JT));                   // 1024 blocks, 1D XCD decode
    bicubic_y64<<<grid, 256, 0, stream>>>(values, g0, g1, out);
}

// Round 5
// 72.303 us; speedup vs baseline: 1.5585x; 1.5585x over previous
//
#include <hip/hip_runtime.h>

// Problem constants (match reference)
#define C_   64
#define H_   256
#define W_   256
#define L0_  1024   // j axis (g0 -> y taps)
#define L1_  1024   // i axis (g1 -> x taps)
#define JT   32     // j-tile per block
#define ROWP 33     // padded hy row stride (floats): kills swizzle VALU and
                    // makes tap rows a compile-time +132B ds_read offset
#define HYR  259    // hy rows: xk = x_tap + 1, x_tap in [-1, 257] (border dup)

// Bicubic tap weights, matches PyTorch grid_sample
// (bicubic, padding_mode='border', align_corners=True), A = -0.75.
__device__ __forceinline__ void cubic_weights(float t, float w[4]) {
    const float A = -0.75f;
    float t2 = t * t, t3 = t2 * t;
    w[0] = A * (t3 - 2.0f * t2 + t);
    w[1] = (A + 2.0f) * t3 - (A + 3.0f) * t2 + 1.0f;
    float s = 1.0f - t, s2 = s * s;
    w[2] = (A + 2.0f) * s2 * s - (A + 3.0f) * s2 + 1.0f;
    float u = 2.0f - t, u2 = u * u;
    w[3] = A * u2 * u - 5.0f * A * u2 + 8.0f * A * u - 4.0f * A;
}

// Y-FIRST separable bicubic. Identical structure to the 75.3us round-1 kernel
// (grid, phase-1 loads, 2-rows-per-instr tap reads, stores, occupancy); the
// only changes remove LDS ops from the phase-2 critical pipe (per-CU shared):
//   - padded [259][33] hy layout: conflict-free without XOR swizzle; the 4
//     taps become ONE address + ds_read_b32 offset:{0,132,264,396}.
//   - no xip table: row index packed into low 8 mantissa bits of w.w
//     (|w3|<=0.07 -> perturbation ~2e-6, negligible), so the per-iter table
//     traffic is a single b128 read at 2 consecutive addresses.
// LDS/iter: 41 cyc -> ~31 cyc (pipe-bound => ~25% faster).
__global__ __launch_bounds__(256, 3) void bicubic_pad(const float* __restrict__ v,
                                                      const float* __restrict__ g0,
                                                      const float* __restrict__ g1,
                                                      float* __restrict__ out) {
    __shared__ float  hy[HYR * ROWP];   // 34.2 KB
    __shared__ float4 xw[L1_];          // 16 KB  (total 49.4 KB -> 3 blocks/CU)

    const int t  = threadIdx.x;
    const int c  = blockIdx.y;
    const int j0 = blockIdx.x * JT;

    // ---- x-tap table: 4 i's per thread; ix packed into w.w low bits ----
    {
        const int ib = t * 4;
#pragma unroll
        for (int s = 0; s < 4; ++s) {
            int i = ib + s;
            float x  = (g1[i] + 1.0f) * 0.5f * (float)(W_ - 1);
            float x0 = floorf(x);
            int   ix = min(max((int)x0, 0), W_ - 1);   // safety clamp
            float w4[4]; cubic_weights(x - x0, w4);
            unsigned b3 = (__float_as_uint(w4[3]) & 0xFFFFFF00u) | (unsigned)ix;
            xw[i] = make_float4(w4[0], w4[1], w4[2], __uint_as_float(b3));
        }
    }

    const int lane = t & 63;
    const int wv   = t >> 6;

    // ---- phase 1: y-interp (identical to round 1, padded write target) ----
    {
        const int x1 = lane;
        const float* vc = v + (size_t)c * (H_ * W_);
#pragma unroll
        for (int jj = 0; jj < JT / 4; ++jj) {
            int j = wv * (JT / 4) + jj;            // uniform per wave
            float xg = (g0[j0 + j] + 1.0f) * 0.5f * (float)(H_ - 1);
            float x0 = floorf(xg);
            int   iy = (int)x0;
            float wy[4]; cubic_weights(xg - x0, wy);
            const float* r0 = vc + min(max(iy - 1, 0), H_ - 1) * W_;
            const float* r1 = vc + min(max(iy,     0), H_ - 1) * W_;
            const float* r2 = vc + min(max(iy + 1, 0), H_ - 1) * W_;
            const float* r3 = vc + min(max(iy + 2, 0), H_ - 1) * W_;
#pragma unroll
            for (int k = 0; k < 4; ++k) {
                int x_ = x1 + 64 * k;              // 256B contiguous loads
                float val = wy[0] * r0[x_] + wy[1] * r1[x_]
                          + wy[2] * r2[x_] + wy[3] * r3[x_];
                hy[(x_ + 1) * ROWP + j] = val;     // banks (x+1+j)&31: no conflict
                if (x_ == 0)   hy[j] = val;        // pad row 0   (x = -1 clamp)
                if (x_ == 255) {                   // pad rows 257,258 (x>255 clamp)
                    hy[257 * ROWP + j] = val;
                    hy[258 * ROWP + j] = val;
                }
            }
        }
    }
    __syncthreads();

    // ---- phase 2: x-interp; 2 i's per wave-instr (validated pattern) ----
    {
        const int jl    = t & 31;                  // lane -> j within tile
        const int ihalf = (t >> 5) & 1;            // two i's per wave-instr
        int i = wv * 256 + ihalf;                  // wave owns 256 consecutive i
        float* op = out + (size_t)c * ((size_t)L1_ * L0_)
                  + (size_t)i * L0_ + j0 + jl;
#pragma unroll 4
        for (int it = 0; it < 128; ++it, i += 2, op += 2 * L0_) {
            float4 w = xw[i];                      // b128, 2 consecutive addrs
            int xk0 = (int)(__float_as_uint(w.w) & 0xFFu);  // tap base row
            const float* hp = &hy[xk0 * ROWP + jl];
            // rows xk0..xk0+3 = image x (ix-1..ix+2) border-clamped via pad rows;
            // compile-time +132B offsets -> 4x ds_read_b32 offset:{0,132,264,396}
            float o = w.x * hp[0]
                    + w.y * hp[ROWP]
                    + w.z * hp[2 * ROWP]
                    + w.w * hp[3 * ROWP];
            *op = o;                               // 2x128B contiguous store
        }
    }
}

extern "C" void kernel_launch(void* const* d_in, const int* in_sizes, int n_in,
                              void* d_out, int out_size, void* d_ws, size_t ws_size,
                              hipStream_t stream) {
    const float* values = (const float*)d_in[0];  // (1, C, H, W) fp32
    const float* g0     = (const float*)d_in[1];  // (L0,) fp32 -> y axis
    const float* g1     = (const float*)d_in[2];  // (L1,) fp32 -> x axis
    float* out          = (float*)d_out;          // (1, C, L1, L0) fp32

    dim3 grid(L0_ / JT, C_);   // (32, 64) = 2048 blocks, same as round 1
    bicubic_pad<<<grid, 256, 0, stream>>>(values, g0, g1, out);
}

// Round 6
// 70.464 us; speedup vs baseline: 1.5992x; 1.0261x over previous
//
#include <hip/hip_runtime.h>

// Problem constants (match reference)
#define C_   64
#define H_   256
#define W_   256
#define L0_  1024   // j axis (g0 -> y taps)
#define L1_  1024   // i axis (g1 -> x taps)
#define JT   32     // j-tile per block
#define ROWP 33     // padded hy row stride (units of float2): conflict-free,
                    // taps at compile-time +264B ds_read offsets
#define HYR  259    // hy rows: xk = x_tap + 1, x_tap in [-1, 257] (border dup)

// Bicubic tap weights, matches PyTorch grid_sample
// (bicubic, padding_mode='border', align_corners=True), A = -0.75.
__device__ __forceinline__ void cubic_weights(float t, float w[4]) {
    const float A = -0.75f;
    float t2 = t * t, t3 = t2 * t;
    w[0] = A * (t3 - 2.0f * t2 + t);
    w[1] = (A + 2.0f) * t3 - (A + 3.0f) * t2 + 1.0f;
    float s = 1.0f - t, s2 = s * s;
    w[2] = (A + 2.0f) * s2 * s - (A + 3.0f) * s2 + 1.0f;
    float u = 2.0f - t, u2 = u * u;
    w[3] = A * u2 * u - 5.0f * A * u2 + 8.0f * A * u - 4.0f * A;
}

// Y-FIRST separable bicubic, CHANNEL-PAIRED (R5 structure, float2 LDS unit).
//   Each block handles 2 channels; every phase-2 LDS instruction keeps R5's
//   validated shape (2 contiguous row-segments per tap instr, 2-addr broadcast
//   tables, 2x128B stores) but yields 128 outputs instead of 64 -> per-output
//   LDS instruction count exactly halves.
//   Table is {w0,w1} float2 + {w2 | ix} packed; w3 = 1-w0-w1-w2 recomputed on
//   the (idle) VALU. LDS = 66.8 + 8 + 4 = 78.8 KB -> 2 blocks/CU (8 waves).
__global__ __launch_bounds__(256, 2) void bicubic_pair(const float* __restrict__ v,
                                                       const float* __restrict__ g0,
                                                       const float* __restrict__ g1,
                                                       float* __restrict__ out) {
    __shared__ float2 hy2[HYR * ROWP];  // 66.8 KB: {ch0,ch1} per (xk, j)
    __shared__ float2 wAB[L1_];         //  8 KB: {w0, w1} per i
    __shared__ float  wC [L1_];         //  4 KB: w2 with ix in low 8 mantissa bits

    const int t  = threadIdx.x;
    const int c0 = blockIdx.y * 2;      // channel pair
    const int j0 = blockIdx.x * JT;

    // ---- x-tap table: 4 i's per thread ----
    {
        const int ib = t * 4;
#pragma unroll
        for (int s = 0; s < 4; ++s) {
            int i = ib + s;
            float x  = (g1[i] + 1.0f) * 0.5f * (float)(W_ - 1);
            float x0 = floorf(x);
            int   ix = min(max((int)x0, 0), W_ - 1);   // safety clamp
            float w4[4]; cubic_weights(x - x0, w4);
            wAB[i] = make_float2(w4[0], w4[1]);
            wC[i]  = __uint_as_float((__float_as_uint(w4[2]) & 0xFFFFFF00u)
                                     | (unsigned)ix);
        }
    }

    const int lane = t & 63;
    const int wv   = t >> 6;

    // ---- phase 1: y-interp both channels (R5 pattern, float2 writes) ----
    {
        const float* vA = v + (size_t)c0 * (H_ * W_);
        const float* vB = vA + (H_ * W_);
#pragma unroll
        for (int jj = 0; jj < JT / 4; ++jj) {
            int j = wv * (JT / 4) + jj;            // uniform per wave
            float xg = (g0[j0 + j] + 1.0f) * 0.5f * (float)(H_ - 1);
            float x0 = floorf(xg);
            int   iy = (int)x0;
            float wy[4]; cubic_weights(xg - x0, wy);
            const int y0 = min(max(iy - 1, 0), H_ - 1) * W_;
            const int y1 = min(max(iy,     0), H_ - 1) * W_;
            const int y2 = min(max(iy + 1, 0), H_ - 1) * W_;
            const int y3 = min(max(iy + 2, 0), H_ - 1) * W_;
#pragma unroll
            for (int k = 0; k < 4; ++k) {
                int x_ = lane + 64 * k;            // 256B contiguous loads
                float a = wy[0] * vA[y0 + x_] + wy[1] * vA[y1 + x_]
                        + wy[2] * vA[y2 + x_] + wy[3] * vA[y3 + x_];
                float b = wy[0] * vB[y0 + x_] + wy[1] * vB[y1 + x_]
                        + wy[2] * vB[y2 + x_] + wy[3] * vB[y3 + x_];
                float2 val = make_float2(a, b);
                hy2[(x_ + 1) * ROWP + j] = val;    // banks (2xk+2j)&31: no conflict
                if (x_ == 0)   hy2[j] = val;       // pad row 0   (x = -1 clamp)
                if (x_ == 255) {                   // pad rows 257,258 (x>255 clamp)
                    hy2[257 * ROWP + j] = val;
                    hy2[258 * ROWP + j] = val;
                }
            }
        }
    }
    __syncthreads();

    // ---- phase 2: x-interp; 2 i's per wave-instr; 128 outputs per iter ----
    {
        const int jl    = t & 31;                  // lane -> j within tile
        const int ihalf = (t >> 5) & 1;            // two i's per wave-instr
        int i = wv * 256 + ihalf;                  // wave owns 256 consecutive i
        float* o0 = out + (size_t)c0 * ((size_t)L1_ * L0_)
                  + (size_t)i * L0_ + j0 + jl;
        float* o1 = o0 + (size_t)L1_ * L0_;
#pragma unroll 4
        for (int it = 0; it < 128; ++it, i += 2, o0 += 2 * L0_, o1 += 2 * L0_) {
            float2 ab = wAB[i];                    // b64, 2-addr broadcast
            float  cw = wC[i];                     // b32, 2-addr broadcast
            int    ix = (int)(__float_as_uint(cw) & 0xFFu);
            float  w3 = 1.0f - ab.x - ab.y - cw;   // weights sum to 1
            const float2* hp = &hy2[ix * ROWP + jl];
            // taps: rows ix..ix+3; per half-wave 256B contiguous; +264B offsets
            float2 h0 = hp[0];
            float2 h1 = hp[ROWP];
            float2 h2 = hp[2 * ROWP];
            float2 h3 = hp[3 * ROWP];
            *o0 = ab.x * h0.x + ab.y * h1.x + cw * h2.x + w3 * h3.x;
            *o1 = ab.x * h0.y + ab.y * h1.y + cw * h2.y + w3 * h3.y;
        }
    }
}

extern "C" void kernel_launch(void* const* d_in, const int* in_sizes, int n_in,
                              void* d_out, int out_size, void* d_ws, size_t ws_size,
                              hipStream_t stream) {
    const float* values = (const float*)d_in[0];  // (1, C, H, W) fp32
    const float* g0     = (const float*)d_in[1];  // (L0,) fp32 -> y axis
    const float* g1     = (const float*)d_in[2];  // (L1,) fp32 -> x axis
    float* out          = (float*)d_out;          // (1, C, L1, L0) fp32

    dim3 grid(L0_ / JT, C_ / 2);   // (32, 32) = 1024 blocks
    bicubic_pair<<<grid, 256, 0, stream>>>(values, g0, g1, out);
}